// Round 1
// 1124.857 us; speedup vs baseline: 1.0319x; 1.0319x over previous
//
#include <hip/hip_runtime.h>
#include <hip/hip_bf16.h>
#include <stdint.h>

typedef unsigned short ushort_t;
typedef __attribute__((ext_vector_type(8))) short short8;
typedef __attribute__((ext_vector_type(4))) float float4v;
typedef __attribute__((ext_vector_type(8))) ushort_t ushort8;

#define BM 256
#define BN 256
#define BK 64

// ---------------------------------------------------------------------------
// async global->LDS 16B copy (wave-uniform LDS base + lane*16 semantics)
// ---------------------------------------------------------------------------
__device__ __forceinline__ void async_copy16(const void* g, void* l) {
  __builtin_amdgcn_global_load_lds(
      (__attribute__((address_space(1))) void*)g,
      (__attribute__((address_space(3))) void*)l,
      16, 0, 0);
}

// ---------------------------------------------------------------------------
// fp32 -> bf16 (RNE) conversion, 8 elements / thread, 16B stores
// ---------------------------------------------------------------------------
__device__ __forceinline__ ushort_t f32_to_bf16_rne(float f) {
  union { float f; uint32_t u; } v; v.f = f;
  uint32_t u = v.u;
  u += 0x7FFFu + ((u >> 16) & 1u);
  return (ushort_t)(u >> 16);
}

__global__ __launch_bounds__(256) void cvt_f32_bf16_kernel(
    const float* __restrict__ in, ushort_t* __restrict__ out, int n8) {
  int i = blockIdx.x * 256 + threadIdx.x;
  if (i >= n8) return;
  const float4v* in4 = (const float4v*)in;
  float4v a = in4[2 * i];
  float4v b = in4[2 * i + 1];
  ushort8 o;
  o[0] = f32_to_bf16_rne(a[0]); o[1] = f32_to_bf16_rne(a[1]);
  o[2] = f32_to_bf16_rne(a[2]); o[3] = f32_to_bf16_rne(a[3]);
  o[4] = f32_to_bf16_rne(b[0]); o[5] = f32_to_bf16_rne(b[1]);
  o[6] = f32_to_bf16_rne(b[2]); o[7] = f32_to_bf16_rne(b[3]);
  ((ushort8*)out)[i] = o;
}

// ---------------------------------------------------------------------------
// 256x256 8-phase bf16 MFMA GEMM (m201-style template):
//   Y[M,N] = Xb[M,K] * Ab[N,K]^T + bias[N]
// 512 threads = 8 waves (2M x 4N), per-wave 128x64 output, BK=64.
// LDS 128 KiB: {A,B} x dbuf(2) x half(128x64 bf16), rows XOR-swizzled:
//   byte ^= (row&7)<<4  (fixes the 128B-row-stride ds_read_b128 bank conflict).
// global_load_lds writes LINEAR dest; the global SOURCE is pre-swizzled with
// the same involution so swizzled reads return logical data (rule 21).
// Staging rotation gives every region >=5 phases issue->first-read slack, so
// a uniform s_waitcnt vmcnt(8) (2 loads/phase x 4 phases in flight) before
// each phase-closing barrier is sufficient -- never vmcnt(0) in the loop.
// ---------------------------------------------------------------------------

#define STAGE_A(buf_, kt_, mh_) do {                                          \
  const int _k0 = (kt_) * BK;                                                 \
  async_copy16(xsrc + (size_t)((mh_) * 64) * K + _k0,                         \
               &As[buf_][0][((mh_) * 64 + wave8) * 64]);                      \
  async_copy16(xsrc + (size_t)((mh_) * 64 + 128) * K + _k0,                   \
               &As[buf_][1][((mh_) * 64 + wave8) * 64]);                      \
} while (0)

#define STAGE_B(buf_, kt_, nh_) do {                                          \
  const int _k0 = (kt_) * BK;                                                 \
  async_copy16(bsrc + (size_t)((nh_) * 32) * K + _k0,                         \
               &Bs[buf_][0][(bq64 + (nh_) * 32 + bs8) * 64]);                 \
  async_copy16(bsrc + (size_t)((nh_) * 32 + 128) * K + _k0,                   \
               &Bs[buf_][1][(bq64 + (nh_) * 32 + bs8) * 64]);                 \
} while (0)

// One phase: 12 ds_read_b128 | 2 global_load_lds | bar | lgkm(0) | 16 MFMA |
//            vmcnt(8) | bar.  (mh_, nh_) selects the C-quadrant, full BK=64.
#define PHASE(buf_, mh_, nh_, STAGE_STMT) do {                                \
  short8 _a[4][2]; short8 _b[2][2];                                           \
  const char* _ab = ((const char*)&As[buf_][wr][0]) + ((mh_)*64 + l15) * 128; \
  const char* _bb = ((const char*)&Bs[buf_][wch][0])                          \
                    + (wc1 * 64 + (nh_) * 32 + l15) * 128;                    \
  _Pragma("unroll")                                                           \
  for (int _mi = 0; _mi < 4; ++_mi) {                                         \
    _a[_mi][0] = *(const short8*)(_ab + _mi * 2048 + ko0);                    \
    _a[_mi][1] = *(const short8*)(_ab + _mi * 2048 + ko1);                    \
  }                                                                           \
  _Pragma("unroll")                                                           \
  for (int _ni = 0; _ni < 2; ++_ni) {                                         \
    _b[_ni][0] = *(const short8*)(_bb + _ni * 2048 + ko0);                    \
    _b[_ni][1] = *(const short8*)(_bb + _ni * 2048 + ko1);                    \
  }                                                                           \
  STAGE_STMT;                                                                 \
  __builtin_amdgcn_s_barrier();                                               \
  asm volatile("s_waitcnt lgkmcnt(0)" ::: "memory");                          \
  __builtin_amdgcn_sched_barrier(0);                                          \
  __builtin_amdgcn_s_setprio(1);                                              \
  _Pragma("unroll")                                                           \
  for (int _ks = 0; _ks < 2; ++_ks)                                           \
    _Pragma("unroll")                                                         \
    for (int _mi = 0; _mi < 4; ++_mi)                                         \
      _Pragma("unroll")                                                       \
      for (int _ni = 0; _ni < 2; ++_ni)                                       \
        acc[(mh_) * 4 + _mi][(nh_) * 2 + _ni] =                               \
            __builtin_amdgcn_mfma_f32_16x16x32_bf16(                          \
                _a[_mi][_ks], _b[_ni][_ks],                                   \
                acc[(mh_) * 4 + _mi][(nh_) * 2 + _ni], 0, 0, 0);              \
  __builtin_amdgcn_s_setprio(0);                                              \
  asm volatile("s_waitcnt vmcnt(8)" ::: "memory");                            \
  __builtin_amdgcn_s_barrier();                                               \
  __builtin_amdgcn_sched_barrier(0);                                          \
} while (0)

__global__ __launch_bounds__(512, 2) void gemm_bf16_8phase(
    const ushort_t* __restrict__ Xb,   // [M,K] bf16
    const ushort_t* __restrict__ Ab,   // [N,K] bf16
    const float* __restrict__ bias,    // [N]
    float* __restrict__ Y,             // [M,N] fp32
    int M, int N, int K) {
  __shared__ __attribute__((aligned(16))) ushort_t As[2][2][128 * 64];
  __shared__ __attribute__((aligned(16))) ushort_t Bs[2][2][128 * 64];

  const int tid  = threadIdx.x;
  const int lane = tid & 63;
  const int wave = tid >> 6;       // 0..7
  const int wr   = wave >> 2;      // 0..1  A-half / output 128-row slab
  const int wc   = wave & 3;       // 0..3  output 64-col slab
  const int wch  = wc >> 1;        // B-half for reads
  const int wc1  = wc & 1;

  // bijective XCD-aware block swizzle (nwg = 1024 here, divisible by 8)
  const int nbx = gridDim.x;
  const int nwg = gridDim.x * gridDim.y;
  int flat = blockIdx.y * nbx + blockIdx.x;
  if ((nwg & 7) == 0) {
    const int cpx = nwg >> 3;
    flat = (flat & 7) * cpx + (flat >> 3);
  }
  const int m0 = (flat / nbx) * BM;
  const int n0 = (flat % nbx) * BN;

  // read-side swizzled k-offsets: slot(3b) = ks*4+lq, XORed with row&7 (=l15&7)
  const int l15 = lane & 15;
  const int lq  = lane >> 4;
  const int sx  = (l15 & 7) << 4;
  const int ko0 = (lq * 16) ^ sx;        // ks=0
  const int ko1 = (64 + lq * 16) ^ sx;   // ks=1

  // stage-side: dest slot = lane&7 at row ..+(lane>>3); source slot pre-XORed
  const int lr3   = lane >> 3;
  const int ksw8  = ((lane & 7) ^ lr3) * 8;
  const int wave8 = wave * 8;
  const int bq64  = wr * 64;
  const int bs8   = wc * 8;

  const ushort_t* xsrc = Xb + (size_t)(m0 + wave8 + lr3) * K + ksw8;
  const ushort_t* bsrc = Ab + (size_t)(n0 + bq64 + bs8 + lr3) * K + ksw8;

  float4v acc[8][4];
#pragma unroll
  for (int i = 0; i < 8; ++i)
#pragma unroll
    for (int j = 0; j < 4; ++j) acc[i][j] = (float4v){0.f, 0.f, 0.f, 0.f};

  const int NT = K / BK;   // 64

  // prologue: tile0 fully -> buf0; tile1 {A-mh0, B-nh0} -> buf1 (12 loads),
  // drain tile0's 8, leave tile1's 4 in flight (steady-state FIFO shape).
  STAGE_A(0, 0, 0); STAGE_A(0, 0, 1); STAGE_B(0, 0, 0); STAGE_B(0, 0, 1);
  STAGE_A(1, 1, 0); STAGE_B(1, 1, 0);
  asm volatile("s_waitcnt vmcnt(4)" ::: "memory");
  __builtin_amdgcn_s_barrier();
  __builtin_amdgcn_sched_barrier(0);

  // Staging rotation (T = 2*it):
  //  ph1: B-nh1(T+1)->buf1   ph2: A-mh1(T+1)->buf1
  //  ph3: A-mh0(T+2)->buf0   ph4: B-nh0(T+2)->buf0
  //  ph5: B-nh1(T+2)->buf0   ph6: A-mh1(T+2)->buf0
  //  ph7: A-mh0(T+3)->buf1   ph8: B-nh0(T+3)->buf1
  // Every region: freed (all reads lgkm-drained) >=1 phase before its write,
  // and staged >=5 phases before its first read (vmcnt(8) sufficient).
  for (int it = 0; it < NT / 2; ++it) {
    const int tA = 2 * it + 1;
    int tB = 2 * it + 2; if (tB > NT - 1) tB = NT - 1;  // clamp: tail stages
    int tC = 2 * it + 3; if (tC > NT - 1) tC = NT - 1;  // garbage, never read
    PHASE(0, 0, 0, STAGE_B(1, tA, 1));
    PHASE(0, 0, 1, STAGE_A(1, tA, 1));
    PHASE(0, 1, 0, STAGE_A(0, tB, 0));
    PHASE(0, 1, 1, STAGE_B(0, tB, 0));
    PHASE(1, 0, 0, STAGE_B(0, tB, 1));
    PHASE(1, 0, 1, STAGE_A(0, tB, 1));
    PHASE(1, 1, 0, STAGE_A(1, tC, 0));
    PHASE(1, 1, 1, STAGE_B(1, tC, 0));
  }

  // epilogue: C/D layout col=lane&15, row=(lane>>4)*4+reg  [m89-verified]
  const int cn = lane & 15;
  const int rq = (lane >> 4) * 4;
#pragma unroll
  for (int ni = 0; ni < 4; ++ni) {
    const int ncol = n0 + wc * 64 + ni * 16 + cn;
    const float bv = bias[ncol];
#pragma unroll
    for (int mi = 0; mi < 8; ++mi) {
      const int mrow = m0 + wr * 128 + mi * 16 + rq;
      float* yp = Y + (size_t)mrow * N + ncol;
#pragma unroll
      for (int r = 0; r < 4; ++r)
        yp[(size_t)r * N] = acc[mi][ni][r] + bv;
    }
  }
}

// ---------------------------------------------------------------------------
// fallback (only if ws too small / non-divisible shape): naive fp32
// ---------------------------------------------------------------------------
__global__ __launch_bounds__(256) void naive_linear_kernel(
    const float* __restrict__ x, const float* __restrict__ A,
    const float* __restrict__ b, float* __restrict__ y,
    int M, int N, int K) {
  long long idx = (long long)blockIdx.x * 256 + threadIdx.x;
  if (idx >= (long long)M * N) return;
  int m = (int)(idx / N), n = (int)(idx % N);
  float s = b[n];
  const float* xp = x + (size_t)m * K;
  const float* ap = A + (size_t)n * K;
  for (int k = 0; k < K; ++k) s += xp[k] * ap[k];
  y[idx] = s;
}

// ---------------------------------------------------------------------------
extern "C" void kernel_launch(void* const* d_in, const int* in_sizes, int n_in,
                              void* d_out, int out_size, void* d_ws, size_t ws_size,
                              hipStream_t stream) {
  const float* x = (const float*)d_in[0];  // [8,2048,4096] -> [M,K]
  const float* A = (const float*)d_in[1];  // [N,K]
  const float* b = (const float*)d_in[2];  // [N]
  float* y = (float*)d_out;

  const int K = 4096;
  const int N = in_sizes[2];               // 4096
  const int M = in_sizes[0] / K;           // 16384

  const size_t x_elems = (size_t)M * K;
  const size_t a_elems = (size_t)N * K;
  const size_t needed = (x_elems + a_elems) * sizeof(ushort_t);

  if (ws_size >= needed && (M % BM) == 0 && (N % BN) == 0 && (K % BK) == 0) {
    ushort_t* xb = (ushort_t*)d_ws;
    ushort_t* ab = xb + x_elems;

    int nx8 = (int)(x_elems / 8);
    int na8 = (int)(a_elems / 8);
    cvt_f32_bf16_kernel<<<(nx8 + 255) / 256, 256, 0, stream>>>(x, xb, nx8);
    cvt_f32_bf16_kernel<<<(na8 + 255) / 256, 256, 0, stream>>>(A, ab, na8);

    dim3 grid(N / BN, M / BM);  // (16, 64) = 1024 workgroups
    gemm_bf16_8phase<<<grid, 512, 0, stream>>>(xb, ab, b, y, M, N, K);
  } else {
    long long total = (long long)M * N;
    naive_linear_kernel<<<(unsigned)((total + 255) / 256), 256, 0, stream>>>(
        x, A, b, y, M, N, K);
  }
}

// Round 2
// 1052.736 us; speedup vs baseline: 1.1026x; 1.0685x over previous
//
#include <hip/hip_runtime.h>
#include <hip/hip_bf16.h>
#include <stdint.h>

typedef unsigned short ushort_t;
typedef __attribute__((ext_vector_type(8))) short short8;
typedef __attribute__((ext_vector_type(4))) float float4v;
typedef __attribute__((ext_vector_type(8))) ushort_t ushort8;

#define BM 256
#define BN 256
#define BK 64

// ---------------------------------------------------------------------------
// async global->LDS 16B copy (wave-uniform LDS base + lane*16 semantics)
// ---------------------------------------------------------------------------
__device__ __forceinline__ void async_copy16(const void* g, void* l) {
  __builtin_amdgcn_global_load_lds(
      (__attribute__((address_space(1))) void*)g,
      (__attribute__((address_space(3))) void*)l,
      16, 0, 0);
}

// ---------------------------------------------------------------------------
// fp32 -> bf16 (RNE) conversion, 8 elements / thread, 16B stores
// ---------------------------------------------------------------------------
__device__ __forceinline__ ushort_t f32_to_bf16_rne(float f) {
  union { float f; uint32_t u; } v; v.f = f;
  uint32_t u = v.u;
  u += 0x7FFFu + ((u >> 16) & 1u);
  return (ushort_t)(u >> 16);
}

__global__ __launch_bounds__(256) void cvt_f32_bf16_kernel(
    const float* __restrict__ in, ushort_t* __restrict__ out, int n8) {
  int i = blockIdx.x * 256 + threadIdx.x;
  if (i >= n8) return;
  const float4v* in4 = (const float4v*)in;
  float4v a = in4[2 * i];
  float4v b = in4[2 * i + 1];
  ushort8 o;
  o[0] = f32_to_bf16_rne(a[0]); o[1] = f32_to_bf16_rne(a[1]);
  o[2] = f32_to_bf16_rne(a[2]); o[3] = f32_to_bf16_rne(a[3]);
  o[4] = f32_to_bf16_rne(b[0]); o[5] = f32_to_bf16_rne(b[1]);
  o[6] = f32_to_bf16_rne(b[2]); o[7] = f32_to_bf16_rne(b[3]);
  ((ushort8*)out)[i] = o;
}

// ---------------------------------------------------------------------------
// 256x256 8-phase bf16 MFMA GEMM: Y[M,N] = Xb[M,K] * Ab[N,K]^T + bias[N]
// 512 threads = 8 waves (2M x 4N), per-wave 128x64 output, BK=64.
// LDS 128 KiB: {A,B} x dbuf(2) x half(128x64 bf16), XOR-swizzled
//   (byte ^= (row&7)<<4) via pre-swizzled global source + swizzled reads.
// Phase order per buffer: (0,0)->(0,1)->(1,1)->(1,0) with fragment reuse:
//   ph1 reads A(mh0)+B(nh0) [12], ph2 reads B(nh1) [4], ph3 reads A(mh1) [8],
//   ph4 reads nothing -- 24 ds_read_b128 per K-tile per wave (was 48).
// Staging rotation + per-phase vmcnt(8) identical to the verified schedule:
//   every region staged >=5 phases before first read, freed >=1 phase
//   before its write (b0f held in regs through ph4; its only LDS read is ph1).
// ---------------------------------------------------------------------------

#define STAGE_A(buf_, kt_, mh_) do {                                          \
  const int _k0 = (kt_) * BK;                                                 \
  async_copy16(xsrc + (size_t)((mh_) * 64) * K + _k0,                         \
               &As[buf_][0][((mh_) * 64 + wave8) * 64]);                      \
  async_copy16(xsrc + (size_t)((mh_) * 64 + 128) * K + _k0,                   \
               &As[buf_][1][((mh_) * 64 + wave8) * 64]);                      \
} while (0)

#define STAGE_B(buf_, kt_, nh_) do {                                          \
  const int _k0 = (kt_) * BK;                                                 \
  async_copy16(bsrc + (size_t)((nh_) * 32) * K + _k0,                         \
               &Bs[buf_][0][(bq64 + (nh_) * 32 + bs8) * 64]);                 \
  async_copy16(bsrc + (size_t)((nh_) * 32 + 128) * K + _k0,                   \
               &Bs[buf_][1][(bq64 + (nh_) * 32 + bs8) * 64]);                 \
} while (0)

// LDS -> register fragment loads (swizzled read addresses)
#define LDA(buf_, mh_) do {                                                   \
  const char* _ab = ((const char*)&As[buf_][wr][0]) + ((mh_)*64 + l15) * 128; \
  _Pragma("unroll")                                                           \
  for (int _mi = 0; _mi < 4; ++_mi) {                                         \
    af[_mi][0] = *(const short8*)(_ab + _mi * 2048 + ko0);                    \
    af[_mi][1] = *(const short8*)(_ab + _mi * 2048 + ko1);                    \
  }                                                                           \
} while (0)

#define LDB(dst_, buf_, nh_) do {                                             \
  const char* _bb = ((const char*)&Bs[buf_][wch][0])                          \
                    + (wc1 * 64 + (nh_) * 32 + l15) * 128;                    \
  _Pragma("unroll")                                                           \
  for (int _ni = 0; _ni < 2; ++_ni) {                                         \
    dst_[_ni][0] = *(const short8*)(_bb + _ni * 2048 + ko0);                  \
    dst_[_ni][1] = *(const short8*)(_bb + _ni * 2048 + ko1);                  \
  }                                                                           \
} while (0)

#define MM(mh_, nh_, bf_)                                                     \
  _Pragma("unroll")                                                           \
  for (int _ks = 0; _ks < 2; ++_ks)                                           \
    _Pragma("unroll")                                                         \
    for (int _mi = 0; _mi < 4; ++_mi)                                         \
      _Pragma("unroll")                                                       \
      for (int _ni = 0; _ni < 2; ++_ni)                                       \
        acc[(mh_) * 4 + _mi][(nh_) * 2 + _ni] =                               \
            __builtin_amdgcn_mfma_f32_16x16x32_bf16(                          \
                af[_mi][_ks], bf_[_ni][_ks],                                  \
                acc[(mh_) * 4 + _mi][(nh_) * 2 + _ni], 0, 0, 0)

// phase sync wrapper: [frag loads already issued] | stage | bar | lgkm(0) |
//                     setprio(1) MFMA setprio(0) | vmcnt(8) | bar
#define SYNC_MFMA(STAGE_STMT, MFMA_STMT) do {                                 \
  STAGE_STMT;                                                                 \
  __builtin_amdgcn_s_barrier();                                               \
  asm volatile("s_waitcnt lgkmcnt(0)" ::: "memory");                          \
  __builtin_amdgcn_sched_barrier(0);                                          \
  __builtin_amdgcn_s_setprio(1);                                              \
  MFMA_STMT;                                                                  \
  __builtin_amdgcn_s_setprio(0);                                              \
  asm volatile("s_waitcnt vmcnt(8)" ::: "memory");                            \
  __builtin_amdgcn_s_barrier();                                               \
  __builtin_amdgcn_sched_barrier(0);                                          \
} while (0)

__global__ __launch_bounds__(512, 2) void gemm_bf16_8phase(
    const ushort_t* __restrict__ Xb,   // [M,K] bf16
    const ushort_t* __restrict__ Ab,   // [N,K] bf16
    const float* __restrict__ bias,    // [N]
    float* __restrict__ Y,             // [M,N] fp32
    int M, int N, int K) {
  __shared__ __attribute__((aligned(16))) ushort_t As[2][2][128 * 64];
  __shared__ __attribute__((aligned(16))) ushort_t Bs[2][2][128 * 64];

  const int tid  = threadIdx.x;
  const int lane = tid & 63;
  const int wave = tid >> 6;       // 0..7
  const int wr   = wave >> 2;      // 0..1  A-half / output 128-row slab
  const int wc   = wave & 3;       // 0..3  output 64-col slab
  const int wch  = wc >> 1;        // B-half for reads
  const int wc1  = wc & 1;

  // bijective XCD-aware block swizzle (nwg = 1024 here, divisible by 8)
  const int nbx = gridDim.x;
  const int nwg = gridDim.x * gridDim.y;
  int flat = blockIdx.y * nbx + blockIdx.x;
  if ((nwg & 7) == 0) {
    const int cpx = nwg >> 3;
    flat = (flat & 7) * cpx + (flat >> 3);
  }
  const int m0 = (flat / nbx) * BM;
  const int n0 = (flat % nbx) * BN;

  // read-side swizzled k-offsets: slot(3b) = ks*4+lq, XORed with row&7 (=l15&7)
  const int l15 = lane & 15;
  const int lq  = lane >> 4;
  const int sx  = (l15 & 7) << 4;
  const int ko0 = (lq * 16) ^ sx;        // ks=0
  const int ko1 = (64 + lq * 16) ^ sx;   // ks=1

  // stage-side: dest slot = lane&7 at row ..+(lane>>3); source slot pre-XORed
  const int lr3   = lane >> 3;
  const int ksw8  = ((lane & 7) ^ lr3) * 8;
  const int wave8 = wave * 8;
  const int bq64  = wr * 64;
  const int bs8   = wc * 8;

  const ushort_t* xsrc = Xb + (size_t)(m0 + wave8 + lr3) * K + ksw8;
  const ushort_t* bsrc = Ab + (size_t)(n0 + bq64 + bs8 + lr3) * K + ksw8;

  float4v acc[8][4];
#pragma unroll
  for (int i = 0; i < 8; ++i)
#pragma unroll
    for (int j = 0; j < 4; ++j) acc[i][j] = (float4v){0.f, 0.f, 0.f, 0.f};

  const int NT = K / BK;   // 64

  // prologue: tile0 fully -> buf0; tile1 {A-mh0, B-nh0} -> buf1 (12 loads),
  // drain tile0's 8, leave tile1's 4 in flight (steady-state FIFO shape).
  STAGE_A(0, 0, 0); STAGE_A(0, 0, 1); STAGE_B(0, 0, 0); STAGE_B(0, 0, 1);
  STAGE_A(1, 1, 0); STAGE_B(1, 1, 0);
  asm volatile("s_waitcnt vmcnt(4)" ::: "memory");
  __builtin_amdgcn_s_barrier();
  __builtin_amdgcn_sched_barrier(0);

  short8 af[4][2], b0f[2][2], b1f[2][2];

  // Staging rotation (T = 2*it) -- unchanged from verified schedule:
  //  ph1: B-nh1(T+1)->buf1   ph2: A-mh1(T+1)->buf1
  //  ph3: A-mh0(T+2)->buf0   ph4: B-nh0(T+2)->buf0
  //  ph5: B-nh1(T+2)->buf0   ph6: A-mh1(T+2)->buf0
  //  ph7: A-mh0(T+3)->buf1   ph8: B-nh0(T+3)->buf1
  for (int it = 0; it < NT / 2; ++it) {
    const int tA = 2 * it + 1;
    int tB = 2 * it + 2; if (tB > NT - 1) tB = NT - 1;  // clamp: tail stages
    int tC = 2 * it + 3; if (tC > NT - 1) tC = NT - 1;  // garbage, never read
    // ---- buf0 (K-tile T) ----
    LDA(0, 0); LDB(b0f, 0, 0);
    SYNC_MFMA(STAGE_B(1, tA, 1), MM(0, 0, b0f));
    LDB(b1f, 0, 1);
    SYNC_MFMA(STAGE_A(1, tA, 1), MM(0, 1, b1f));
    LDA(0, 1);
    SYNC_MFMA(STAGE_A(0, tB, 0), MM(1, 1, b1f));
    SYNC_MFMA(STAGE_B(0, tB, 0), MM(1, 0, b0f));
    // ---- buf1 (K-tile T+1) ----
    LDA(1, 0); LDB(b0f, 1, 0);
    SYNC_MFMA(STAGE_B(0, tB, 1), MM(0, 0, b0f));
    LDB(b1f, 1, 1);
    SYNC_MFMA(STAGE_A(0, tB, 1), MM(0, 1, b1f));
    LDA(1, 1);
    SYNC_MFMA(STAGE_A(1, tC, 0), MM(1, 1, b1f));
    SYNC_MFMA(STAGE_B(1, tC, 0), MM(1, 0, b0f));
  }

  // epilogue: C/D layout col=lane&15, row=(lane>>4)*4+reg  [m89-verified]
  const int cn = lane & 15;
  const int rq = (lane >> 4) * 4;
#pragma unroll
  for (int ni = 0; ni < 4; ++ni) {
    const int ncol = n0 + wc * 64 + ni * 16 + cn;
    const float bv = bias[ncol];
#pragma unroll
    for (int mi = 0; mi < 8; ++mi) {
      const int mrow = m0 + wr * 128 + mi * 16 + rq;
      float* yp = Y + (size_t)mrow * N + ncol;
#pragma unroll
      for (int r = 0; r < 4; ++r)
        yp[(size_t)r * N] = acc[mi][ni][r] + bv;
    }
  }
}

// ---------------------------------------------------------------------------
// fallback (only if ws too small / non-divisible shape): naive fp32
// ---------------------------------------------------------------------------
__global__ __launch_bounds__(256) void naive_linear_kernel(
    const float* __restrict__ x, const float* __restrict__ A,
    const float* __restrict__ b, float* __restrict__ y,
    int M, int N, int K) {
  long long idx = (long long)blockIdx.x * 256 + threadIdx.x;
  if (idx >= (long long)M * N) return;
  int m = (int)(idx / N), n = (int)(idx % N);
  float s = b[n];
  const float* xp = x + (size_t)m * K;
  const float* ap = A + (size_t)n * K;
  for (int k = 0; k < K; ++k) s += xp[k] * ap[k];
  y[idx] = s;
}

// ---------------------------------------------------------------------------
extern "C" void kernel_launch(void* const* d_in, const int* in_sizes, int n_in,
                              void* d_out, int out_size, void* d_ws, size_t ws_size,
                              hipStream_t stream) {
  const float* x = (const float*)d_in[0];  // [8,2048,4096] -> [M,K]
  const float* A = (const float*)d_in[1];  // [N,K]
  const float* b = (const float*)d_in[2];  // [N]
  float* y = (float*)d_out;

  const int K = 4096;
  const int N = in_sizes[2];               // 4096
  const int M = in_sizes[0] / K;           // 16384

  const size_t x_elems = (size_t)M * K;
  const size_t a_elems = (size_t)N * K;
  const size_t needed = (x_elems + a_elems) * sizeof(ushort_t);

  if (ws_size >= needed && (M % BM) == 0 && (N % BN) == 0 && (K % BK) == 0) {
    ushort_t* xb = (ushort_t*)d_ws;
    ushort_t* ab = xb + x_elems;

    int nx8 = (int)(x_elems / 8);
    int na8 = (int)(a_elems / 8);
    cvt_f32_bf16_kernel<<<(nx8 + 255) / 256, 256, 0, stream>>>(x, xb, nx8);
    cvt_f32_bf16_kernel<<<(na8 + 255) / 256, 256, 0, stream>>>(A, ab, na8);

    dim3 grid(N / BN, M / BM);  // (16, 64) = 1024 workgroups
    gemm_bf16_8phase<<<grid, 512, 0, stream>>>(xb, ab, b, y, M, N, K);
  } else {
    long long total = (long long)M * N;
    naive_linear_kernel<<<(unsigned)((total + 255) / 256), 256, 0, stream>>>(
        x, A, b, y, M, N, K);
  }
}